// Round 11
// baseline (1044.353 us; speedup 1.0000x reference)
//
#include <hip/hip_runtime.h>
#include <cfloat>

#define N_ROWS 16384
#define DDIM   768
#define KCOLS  10000
#define KPAD   10112   // 79 * 128

#define TRANSC_BLKS (KPAD / 32 * (DDIM / 32))   // 316*24 = 7584
#define CONVX_BLKS  (N_ROWS * 96 / 256)         // 6144
#define CNORM_BLKS  (KPAD / 64)                 // 158

typedef __attribute__((ext_vector_type(4))) float f32x4;
typedef __attribute__((ext_vector_type(8))) short s16x8;
typedef unsigned long long u64;
typedef unsigned int u32;

__device__ __forceinline__ u32 fsort(float f) {
  u32 u = __float_as_uint(f);
  return (u & 0x80000000u) ? ~u : (u | 0x80000000u);
}
__device__ __forceinline__ float funsort(u32 u) {
  u32 b = (u & 0x80000000u) ? (u ^ 0x80000000u) : ~u;
  return __uint_as_float(b);
}
__device__ __forceinline__ unsigned short f2bf(float f) {  // RNE
  u32 b = __float_as_uint(f);
  return (unsigned short)((b + 0x7fffu + ((b >> 16) & 1u)) >> 16);
}
__device__ __forceinline__ float bf2f(unsigned short s) {
  return __uint_as_float(((u32)s) << 16);
}

// ============================ fused pre-pass ============================
__global__ __launch_bounds__(256) void prep_kernel(
    const float* __restrict__ X, const float* __restrict__ C,
    unsigned short* __restrict__ Xb, unsigned short* __restrict__ Cb,
    float* __restrict__ Ct, float* __restrict__ cn, u64* __restrict__ best) {
  __shared__ float smem[32 * 33];
  const int bid = blockIdx.x;
  const int t = threadIdx.x;

  if (bid < TRANSC_BLKS) {
    const int kk = (bid % (KPAD / 32)) * 32;
    const int dd = (bid / (KPAD / 32)) * 32;
    const int tx = t & 31, ty = t >> 5;
#pragma unroll
    for (int j = 0; j < 4; ++j) {
      int d = dd + ty + j * 8, k = kk + tx;
      smem[(ty + j * 8) * 33 + tx] = (k < KCOLS) ? C[(size_t)d * KCOLS + k] : 0.f;
    }
    __syncthreads();
#pragma unroll
    for (int j = 0; j < 4; ++j) {
      int k = kk + ty + j * 8, d = dd + tx;
      float v = smem[tx * 33 + (ty + j * 8)];
      Cb[(size_t)k * DDIM + (d ^ ((k & 7) << 3))] = f2bf(v);
      Ct[(size_t)k * DDIM + d] = v;
    }
  } else if (bid < TRANSC_BLKS + CONVX_BLKS) {
    int i = (bid - TRANSC_BLKS) * 256 + t;
    if (i < N_ROWS) best[i] = ~0ULL;
    int row = i / 96;
    int pc  = i % 96;
    int lc  = pc ^ (row & 7);
    const float4* p = (const float4*)(X + (size_t)row * DDIM + lc * 8);
    float4 a = p[0], b = p[1];
    union { unsigned short s[8]; uint4 v; } o;
    o.s[0] = f2bf(a.x); o.s[1] = f2bf(a.y); o.s[2] = f2bf(a.z); o.s[3] = f2bf(a.w);
    o.s[4] = f2bf(b.x); o.s[5] = f2bf(b.y); o.s[6] = f2bf(b.z); o.s[7] = f2bf(b.w);
    *((uint4*)Xb + i) = o.v;
  } else {
    const int kb = bid - TRANSC_BLKS - CONVX_BLKS;
    const int tx = t & 63, ty = t >> 6;
    const int k = kb * 64 + tx;
    float s = 0.f;
    if (k < KCOLS) {
      const float* p = C + (size_t)(ty * 192) * KCOLS + k;
      for (int d = 0; d < 192; ++d) {
        float v = p[(size_t)d * KCOLS];
        s = fmaf(v, v, s);
      }
    }
    smem[ty * 64 + tx] = s;
    __syncthreads();
    if (ty == 0)
      cn[k] = (k < KCOLS)
                  ? ((smem[tx] + smem[64 + tx]) + (smem[128 + tx] + smem[192 + tx]))
                  : FLT_MAX;
  }
}

#define GLOAD_LDS16(gp, lp)                                                     \
  __builtin_amdgcn_global_load_lds((const __attribute__((address_space(1))) void*)(gp), \
                                   (__attribute__((address_space(3))) void*)(lp), 16, 0, 0)

// ==================== MFMA seed: 128 rows x 64 sampled centroids ====================
// Candidates k = j*158 (j=0..63). B rows read from swizzled Cb; stored swizzle key
// for row j is (j*158)&7 = (j*6)&7, so read-side key = (lr*6)&7 (n*96 = 0 mod 8).
// Plain store to amin (single writer per row) -> no init needed, deterministic.
__global__ __launch_bounds__(256) void seed_mfma(
    const unsigned short* __restrict__ Xb, const unsigned short* __restrict__ Cb,
    const float* __restrict__ cn, u32* __restrict__ amin) {
  __shared__ unsigned short As[128 * 64];
  __shared__ unsigned short Bs[64 * 64];

  const int t = threadIdx.x;
  const int lane = t & 63, wave = t >> 6;
  const int n0 = blockIdx.x * 128;
  const int lr = lane & 15, lg = lane >> 4;
  const int srow = lane >> 3, schunk = lane & 7;
  const int xra = lr & 7;              // A read swizzle key
  const int xrb = (lr * 6) & 7;        // B read swizzle key (k = j*158)

  f32x4 acc[2][4];
  f32x4 z = {0.f, 0.f, 0.f, 0.f};
#pragma unroll
  for (int m = 0; m < 2; ++m)
#pragma unroll
    for (int n = 0; n < 4; ++n) acc[m][n] = z;

  const unsigned short* gA = Xb + (size_t)(n0 + wave * 32 + srow) * DDIM + schunk * 8;
  const unsigned short* gB = Cb + (size_t)(wave * 16 + srow) * 158 * DDIM + schunk * 8;

  for (int it = 0; it < DDIM / 64; ++it) {
#pragma unroll
    for (int i = 0; i < 4; ++i)
      GLOAD_LDS16(gA + (size_t)i * 8 * DDIM, As + (wave * 32 + i * 8) * 64);
#pragma unroll
    for (int i = 0; i < 2; ++i)
      GLOAD_LDS16(gB + (size_t)i * 8 * 158 * DDIM, Bs + (wave * 16 + i * 8) * 64);
    gA += 64; gB += 64;
    __syncthreads();
#pragma unroll
    for (int dk = 0; dk < 2; ++dk) {
      s16x8 af[2], bfr[4];
#pragma unroll
      for (int m = 0; m < 2; ++m)
        af[m] = *(const s16x8*)(As + (wave * 32 + m * 16 + lr) * 64 + (((dk * 4 + lg) ^ xra) * 8));
#pragma unroll
      for (int n = 0; n < 4; ++n)
        bfr[n] = *(const s16x8*)(Bs + (n * 16 + lr) * 64 + (((dk * 4 + lg) ^ xrb) * 8));
#pragma unroll
      for (int m = 0; m < 2; ++m)
#pragma unroll
        for (int n = 0; n < 4; ++n)
          acc[m][n] = __builtin_amdgcn_mfma_f32_16x16x32_bf16(af[m], bfr[n], acc[m][n], 0, 0, 0);
    }
    __syncthreads();
  }

  float cnv[4];
#pragma unroll
  for (int n = 0; n < 4; ++n) cnv[n] = cn[(n * 16 + lr) * 158];

#pragma unroll
  for (int m = 0; m < 2; ++m) {
#pragma unroll
    for (int e = 0; e < 4; ++e) {
      float v = FLT_MAX;
#pragma unroll
      for (int n = 0; n < 4; ++n)
        v = fminf(v, fmaf(-2.f, acc[m][n][e], cnv[n]));
#pragma unroll
      for (int s = 1; s < 16; s <<= 1) v = fminf(v, __shfl_xor(v, s));
      if (lr == 0) amin[n0 + wave * 32 + m * 16 + lg * 4 + e] = fsort(v);
    }
  }
}

// ============================ fused GEMM + argmin ============================

__global__ __launch_bounds__(256, 5) void assign_mfma(
    const unsigned short* __restrict__ Xb, const unsigned short* __restrict__ Cb,
    const float* __restrict__ X32, const float* __restrict__ C32,
    const float* __restrict__ Ct, const float* __restrict__ cn,
    u32* __restrict__ amin, u64* __restrict__ best) {
  __shared__ unsigned short As[128 * 64];   // [row][chunk-swizzled d]
  __shared__ unsigned short Bs[128 * 64];

  const int t = threadIdx.x;
  const int lane = t & 63, wave = t >> 6;
  const int wr = wave >> 1, wc = wave & 1;
  const int n0 = blockIdx.x * 128;
  const int k0 = blockIdx.y * 128;
  const int lr = lane & 15, lg = lane >> 4;
  const int srow = lane >> 3, schunk = lane & 7;
  const int xr = lr & 7;                    // read-side swizzle key (row&7 == lr&7)

  f32x4 acc[4][4];
  f32x4 z = {0.f, 0.f, 0.f, 0.f};
#pragma unroll
  for (int m = 0; m < 4; ++m)
#pragma unroll
    for (int n = 0; n < 4; ++n) acc[m][n] = z;

  const unsigned short* gA = Xb + (size_t)(n0 + wave * 32 + srow) * DDIM + schunk * 8;
  const unsigned short* gB = Cb + (size_t)(k0 + wave * 32 + srow) * DDIM + schunk * 8;

  for (int it = 0; it < DDIM / 64; ++it) {
#pragma unroll
    for (int i = 0; i < 4; ++i) {
      GLOAD_LDS16(gA + (size_t)i * 8 * DDIM, As + (wave * 32 + i * 8) * 64);
      GLOAD_LDS16(gB + (size_t)i * 8 * DDIM, Bs + (wave * 32 + i * 8) * 64);
    }
    gA += 64; gB += 64;
    __syncthreads();
#pragma unroll
    for (int dk = 0; dk < 2; ++dk) {
      s16x8 af[4], bfr[4];
      const int c = (dk * 4 + lg) ^ xr;     // physical chunk
#pragma unroll
      for (int m = 0; m < 4; ++m)
        af[m] = *(const s16x8*)(As + (wr * 64 + m * 16 + lr) * 64 + c * 8);
#pragma unroll
      for (int n = 0; n < 4; ++n)
        bfr[n] = *(const s16x8*)(Bs + (wc * 64 + n * 16 + lr) * 64 + c * 8);
#pragma unroll
      for (int m = 0; m < 4; ++m)
#pragma unroll
        for (int n = 0; n < 4; ++n)
          acc[m][n] = __builtin_amdgcn_mfma_f32_16x16x32_bf16(af[m], bfr[n], acc[m][n], 0, 0, 0);
    }
    __syncthreads();
  }

  // ---------------- epilogue: approx min + exact rescore ----------------
  float cnv[4];
#pragma unroll
  for (int n = 0; n < 4; ++n) cnv[n] = cn[k0 + wc * 64 + n * 16 + lr];

#pragma unroll
  for (int m = 0; m < 4; ++m) {
    float sc[4][4];  // [n][e]
#pragma unroll
    for (int n = 0; n < 4; ++n)
#pragma unroll
      for (int e = 0; e < 4; ++e) sc[n][e] = fmaf(-2.f, acc[m][n][e], cnv[n]);

    float th[4];
#pragma unroll
    for (int e = 0; e < 4; ++e) {
      float v = fminf(fminf(sc[0][e], sc[1][e]), fminf(sc[2][e], sc[3][e]));
      u32 key = fsort(v);
#pragma unroll
      for (int s = 1; s < 16; s <<= 1) {
        u32 o = __shfl_xor(key, s);
        key = key < o ? key : o;
      }
      int row = n0 + wr * 64 + m * 16 + lg * 4 + e;
      u32 mr = key;
      if (lr == 0) {
        u32 old = atomicMin(&amin[row], key);
        mr = old < key ? old : key;
      }
      mr = __shfl(mr, lane & 48);
      th[e] = funsort(mr) + 1.5f;   // margin ~ 7 sigma of bf16-approx error diff
    }

#pragma unroll
    for (int n = 0; n < 4; ++n) {
#pragma unroll
      for (int e = 0; e < 4; ++e) {
        int kq = k0 + wc * 64 + n * 16 + lr;
        bool cand = (kq < KCOLS) && (sc[n][e] <= th[e]);
        u64 mask = __ballot(cand);
        while (mask) {
          int src = (int)__builtin_ctzll(mask);
          mask &= mask - 1;
          int srowg = n0 + wr * 64 + m * 16 + ((src >> 4) & 3) * 4 + e;
          int skg = k0 + wc * 64 + n * 16 + (src & 15);
          float part = 0.f;
          const float* xp = X32 + (size_t)srowg * DDIM + lane;
          if (Ct) {
            const float* cp = Ct + (size_t)skg * DDIM + lane;   // coalesced
#pragma unroll
            for (int i = 0; i < 12; ++i)
              part = fmaf(xp[i * 64], cp[i * 64], part);
          } else {
            const float* cp = C32 + (size_t)lane * KCOLS + skg;
#pragma unroll
            for (int i = 0; i < 12; ++i)
              part = fmaf(xp[i * 64], cp[(size_t)i * 64 * KCOLS], part);
          }
#pragma unroll
          for (int s = 1; s < 64; s <<= 1) part += __shfl_xor(part, s);
          if (lane == 0) {
            float ex = fmaf(-2.f, part, cn[skg]);
            atomicMin(&best[srowg], ((u64)fsort(ex) << 32) | (u32)skg);
          }
        }
      }
    }
  }
}

// ============================ fp32 fallback path ============================

__global__ void cnorm_kernel(const float* __restrict__ C, float* __restrict__ cnorm,
                             int D, int K) {
  int k = blockIdx.x * blockDim.x + threadIdx.x;
  if (k >= K) return;
  float s = 0.f;
  for (int d = 0; d < D; ++d) {
    float v = C[(size_t)d * K + k];
    s = fmaf(v, v, s);
  }
  cnorm[k] = s;
}

__global__ void init_kernel(u64* best, int N) {
  int n = blockIdx.x * blockDim.x + threadIdx.x;
  if (n < N) best[n] = ~0ULL;
}

__global__ __launch_bounds__(256) void assign_kernel(
    const float* __restrict__ X, const float* __restrict__ C,
    const float* __restrict__ cnorm, u64* __restrict__ best,
    int N, int D, int K) {
  __shared__ float Xs[16][128];
  __shared__ float Cs[16][64];
  const int t = threadIdx.x;
  const int tx = t & 15, ty = t >> 4;
  const int k0 = blockIdx.x * 64;
  const int n0 = blockIdx.y * 128;
  float acc[8][4];
#pragma unroll
  for (int i = 0; i < 8; ++i)
#pragma unroll
    for (int j = 0; j < 4; ++j) acc[i][j] = 0.f;
  for (int d0 = 0; d0 < D; d0 += 16) {
#pragma unroll
    for (int v = 0; v < 2; ++v) {
      int f4 = t + v * 256;
      int row = f4 >> 2;
      int dc = (f4 & 3) * 4;
      const float4 xv = *(const float4*)&X[(size_t)(n0 + row) * D + d0 + dc];
      Xs[dc + 0][row] = xv.x; Xs[dc + 1][row] = xv.y;
      Xs[dc + 2][row] = xv.z; Xs[dc + 3][row] = xv.w;
    }
    {
      int d = t >> 4, kc = (t & 15) * 4, k = k0 + kc;
      float4 cv;
      if (k + 3 < K) cv = *(const float4*)&C[(size_t)(d0 + d) * K + k];
      else {
        cv.x = (k + 0 < K) ? C[(size_t)(d0 + d) * K + k + 0] : 0.f;
        cv.y = (k + 1 < K) ? C[(size_t)(d0 + d) * K + k + 1] : 0.f;
        cv.z = (k + 2 < K) ? C[(size_t)(d0 + d) * K + k + 2] : 0.f;
        cv.w = (k + 3 < K) ? C[(size_t)(d0 + d) * K + k + 3] : 0.f;
      }
      *(float4*)&Cs[d][kc] = cv;
    }
    __syncthreads();
#pragma unroll
    for (int d = 0; d < 16; ++d) {
      float4 a0 = *(const float4*)&Xs[d][ty * 8];
      float4 a1 = *(const float4*)&Xs[d][ty * 8 + 4];
      float4 b = *(const float4*)&Cs[d][tx * 4];
      float av[8] = {a0.x, a0.y, a0.z, a0.w, a1.x, a1.y, a1.z, a1.w};
      float bv[4] = {b.x, b.y, b.z, b.w};
#pragma unroll
      for (int i = 0; i < 8; ++i)
#pragma unroll
        for (int j = 0; j < 4; ++j) acc[i][j] = fmaf(av[i], bv[j], acc[i][j]);
    }
    __syncthreads();
  }
  float cnv[4];
#pragma unroll
  for (int j = 0; j < 4; ++j) {
    int k = k0 + tx * 4 + j;
    cnv[j] = (k < K) ? cnorm[k] : 0.f;
  }
#pragma unroll
  for (int i = 0; i < 8; ++i) {
    u64 key = ~0ULL;
#pragma unroll
    for (int j = 0; j < 4; ++j) {
      int k = k0 + tx * 4 + j;
      if (k < K) {
        float score = fmaf(-2.f, acc[i][j], cnv[j]);
        u64 cand = ((u64)fsort(score) << 32) | (unsigned)k;
        key = key < cand ? key : cand;
      }
    }
#pragma unroll
    for (int mk = 8; mk >= 1; mk >>= 1) {
      u64 other = __shfl_xor(key, mk, 16);
      key = key < other ? key : other;
    }
    if (tx == 0) atomicMin(&best[n0 + ty * 8 + i], key);
  }
}

// ---------------- shared output kernel ----------------
__global__ void out_kernel(const u64* __restrict__ best, int* __restrict__ out, int N) {
  int n = blockIdx.x * blockDim.x + threadIdx.x;
  if (n < N) out[n] = (int)(u32)(best[n] & 0xffffffffu);
}

extern "C" void kernel_launch(void* const* d_in, const int* in_sizes, int n_in,
                              void* d_out, int out_size, void* d_ws, size_t ws_size,
                              hipStream_t stream) {
  const float* X = (const float*)d_in[0];  // [N, D]
  const float* C = (const float*)d_in[1];  // [D, K]
  int* out = (int*)d_out;

  // ws layout: best | amin | cnorm | Xb | Cb | Ct
  const size_t OFF_BEST = 0;
  const size_t OFF_AMIN = 131072;
  const size_t OFF_CN   = 196608;
  const size_t OFF_XB   = 262144;
  const size_t OFF_CB   = OFF_XB + (size_t)N_ROWS * DDIM * 2;     // 25427968
  const size_t OFF_CT   = OFF_CB + (size_t)KPAD * DDIM * 2;       // 40960000
  const size_t REQ_A    = OFF_CT + (size_t)KPAD * DDIM * 4;       // 72024064

  if (ws_size >= REQ_A) {
    u64* best = (u64*)((char*)d_ws + OFF_BEST);
    u32* amin = (u32*)((char*)d_ws + OFF_AMIN);
    float* cnp = (float*)((char*)d_ws + OFF_CN);
    unsigned short* Xb = (unsigned short*)((char*)d_ws + OFF_XB);
    unsigned short* Cb = (unsigned short*)((char*)d_ws + OFF_CB);
    float* Ct = (float*)((char*)d_ws + OFF_CT);

    hipLaunchKernelGGL(prep_kernel, dim3(TRANSC_BLKS + CONVX_BLKS + CNORM_BLKS), dim3(256),
                       0, stream, X, C, Xb, Cb, Ct, cnp, best);
    hipLaunchKernelGGL(seed_mfma, dim3(N_ROWS / 128), dim3(256), 0, stream, Xb, Cb, cnp, amin);
    hipLaunchKernelGGL(assign_mfma, dim3(N_ROWS / 128, KPAD / 128), dim3(256), 0, stream,
                       Xb, Cb, X, C, Ct, cnp, amin, best);
    hipLaunchKernelGGL(out_kernel, dim3(64), dim3(256), 0, stream, best, out, N_ROWS);
  } else {
    // fp32 fallback (round-2 passing path)
    u64* best = (u64*)d_ws;
    float* cnorm = (float*)((char*)d_ws + (size_t)N_ROWS * sizeof(u64));
    hipLaunchKernelGGL(init_kernel, dim3(64), dim3(256), 0, stream, best, N_ROWS);
    hipLaunchKernelGGL(cnorm_kernel, dim3((KCOLS + 255) / 256), dim3(256), 0, stream,
                       C, cnorm, DDIM, KCOLS);
    hipLaunchKernelGGL(assign_kernel, dim3((KCOLS + 63) / 64, N_ROWS / 128), dim3(256), 0,
                       stream, X, C, cnorm, best, N_ROWS, DDIM, KCOLS);
    hipLaunchKernelGGL(out_kernel, dim3(64), dim3(256), 0, stream, best, out, N_ROWS);
  }
}

// Round 12
// 402.037 us; speedup vs baseline: 2.5977x; 2.5977x over previous
//
#include <hip/hip_runtime.h>
#include <cfloat>

#define N_ROWS 16384
#define DDIM   768
#define KCOLS  10000
#define KPAD   10112   // 79 * 128

#define TRANSC_BLKS (KPAD / 32 * (DDIM / 32))   // 316*24 = 7584
#define CONVX_BLKS  (N_ROWS * 96 / 256)         // 6144
#define CNORM_BLKS  (KPAD / 64)                 // 158

typedef __attribute__((ext_vector_type(4))) float f32x4;
typedef __attribute__((ext_vector_type(8))) short s16x8;
typedef unsigned long long u64;
typedef unsigned int u32;

__device__ __forceinline__ u32 fsort(float f) {
  u32 u = __float_as_uint(f);
  return (u & 0x80000000u) ? ~u : (u | 0x80000000u);
}
__device__ __forceinline__ float funsort(u32 u) {
  u32 b = (u & 0x80000000u) ? (u ^ 0x80000000u) : ~u;
  return __uint_as_float(b);
}
__device__ __forceinline__ unsigned short f2bf(float f) {  // RNE
  u32 b = __float_as_uint(f);
  return (unsigned short)((b + 0x7fffu + ((b >> 16) & 1u)) >> 16);
}
__device__ __forceinline__ float bf2f(unsigned short s) {
  return __uint_as_float(((u32)s) << 16);
}

// ============================ fused pre-pass ============================
__global__ __launch_bounds__(256) void prep_kernel(
    const float* __restrict__ X, const float* __restrict__ C,
    unsigned short* __restrict__ Xb, unsigned short* __restrict__ Cb,
    float* __restrict__ Ct, float* __restrict__ cn, u64* __restrict__ best) {
  __shared__ float smem[32 * 33];
  const int bid = blockIdx.x;
  const int t = threadIdx.x;

  if (bid < TRANSC_BLKS) {
    const int kk = (bid % (KPAD / 32)) * 32;
    const int dd = (bid / (KPAD / 32)) * 32;
    const int tx = t & 31, ty = t >> 5;
#pragma unroll
    for (int j = 0; j < 4; ++j) {
      int d = dd + ty + j * 8, k = kk + tx;
      smem[(ty + j * 8) * 33 + tx] = (k < KCOLS) ? C[(size_t)d * KCOLS + k] : 0.f;
    }
    __syncthreads();
#pragma unroll
    for (int j = 0; j < 4; ++j) {
      int k = kk + ty + j * 8, d = dd + tx;
      float v = smem[tx * 33 + (ty + j * 8)];
      Cb[(size_t)k * DDIM + (d ^ ((k & 7) << 3))] = f2bf(v);
      Ct[(size_t)k * DDIM + d] = v;
    }
  } else if (bid < TRANSC_BLKS + CONVX_BLKS) {
    int i = (bid - TRANSC_BLKS) * 256 + t;
    if (i < N_ROWS) best[i] = ~0ULL;
    int row = i / 96;
    int pc  = i % 96;
    int lc  = pc ^ (row & 7);
    const float4* p = (const float4*)(X + (size_t)row * DDIM + lc * 8);
    float4 a = p[0], b = p[1];
    union { unsigned short s[8]; uint4 v; } o;
    o.s[0] = f2bf(a.x); o.s[1] = f2bf(a.y); o.s[2] = f2bf(a.z); o.s[3] = f2bf(a.w);
    o.s[4] = f2bf(b.x); o.s[5] = f2bf(b.y); o.s[6] = f2bf(b.z); o.s[7] = f2bf(b.w);
    *((uint4*)Xb + i) = o.v;
  } else {
    const int kb = bid - TRANSC_BLKS - CONVX_BLKS;
    const int tx = t & 63, ty = t >> 6;
    const int k = kb * 64 + tx;
    float s = 0.f;
    if (k < KCOLS) {
      const float* p = C + (size_t)(ty * 192) * KCOLS + k;
      for (int d = 0; d < 192; ++d) {
        float v = p[(size_t)d * KCOLS];
        s = fmaf(v, v, s);
      }
    }
    smem[ty * 64 + tx] = s;
    __syncthreads();
    if (ty == 0)
      cn[k] = (k < KCOLS)
                  ? ((smem[tx] + smem[64 + tx]) + (smem[128 + tx] + smem[192 + tx]))
                  : FLT_MAX;
  }
}

#define GLOAD_LDS16(gp, lp)                                                     \
  __builtin_amdgcn_global_load_lds((const __attribute__((address_space(1))) void*)(gp), \
                                   (__attribute__((address_space(3))) void*)(lp), 16, 0, 0)

// ==================== MFMA seed: 128 rows x 64 sampled centroids ====================
// Candidates k = j*158 (j=0..63). B rows read from swizzled Cb; stored swizzle key
// for row j is (j*158)&7 = (j*6)&7, so read-side key = (lr*6)&7 (n*96 = 0 mod 8).
// Plain store to amin (single writer per row) -> no init needed, deterministic.
__global__ __launch_bounds__(256) void seed_mfma(
    const unsigned short* __restrict__ Xb, const unsigned short* __restrict__ Cb,
    const float* __restrict__ cn, u32* __restrict__ amin) {
  __shared__ unsigned short As[128 * 64];
  __shared__ unsigned short Bs[64 * 64];

  const int t = threadIdx.x;
  const int lane = t & 63, wave = t >> 6;
  const int n0 = blockIdx.x * 128;
  const int lr = lane & 15, lg = lane >> 4;
  const int srow = lane >> 3, schunk = lane & 7;
  const int xra = lr & 7;              // A read swizzle key
  const int xrb = (lr * 6) & 7;        // B read swizzle key (k = j*158)

  f32x4 acc[2][4];
  f32x4 z = {0.f, 0.f, 0.f, 0.f};
#pragma unroll
  for (int m = 0; m < 2; ++m)
#pragma unroll
    for (int n = 0; n < 4; ++n) acc[m][n] = z;

  const unsigned short* gA = Xb + (size_t)(n0 + wave * 32 + srow) * DDIM + schunk * 8;
  const unsigned short* gB = Cb + (size_t)(wave * 16 + srow) * 158 * DDIM + schunk * 8;

  for (int it = 0; it < DDIM / 64; ++it) {
#pragma unroll
    for (int i = 0; i < 4; ++i)
      GLOAD_LDS16(gA + (size_t)i * 8 * DDIM, As + (wave * 32 + i * 8) * 64);
#pragma unroll
    for (int i = 0; i < 2; ++i)
      GLOAD_LDS16(gB + (size_t)i * 8 * 158 * DDIM, Bs + (wave * 16 + i * 8) * 64);
    gA += 64; gB += 64;
    __syncthreads();
#pragma unroll
    for (int dk = 0; dk < 2; ++dk) {
      s16x8 af[2], bfr[4];
#pragma unroll
      for (int m = 0; m < 2; ++m)
        af[m] = *(const s16x8*)(As + (wave * 32 + m * 16 + lr) * 64 + (((dk * 4 + lg) ^ xra) * 8));
#pragma unroll
      for (int n = 0; n < 4; ++n)
        bfr[n] = *(const s16x8*)(Bs + (n * 16 + lr) * 64 + (((dk * 4 + lg) ^ xrb) * 8));
#pragma unroll
      for (int m = 0; m < 2; ++m)
#pragma unroll
        for (int n = 0; n < 4; ++n)
          acc[m][n] = __builtin_amdgcn_mfma_f32_16x16x32_bf16(af[m], bfr[n], acc[m][n], 0, 0, 0);
    }
    __syncthreads();
  }

  float cnv[4];
#pragma unroll
  for (int n = 0; n < 4; ++n) cnv[n] = cn[(n * 16 + lr) * 158];

#pragma unroll
  for (int m = 0; m < 2; ++m) {
#pragma unroll
    for (int e = 0; e < 4; ++e) {
      float v = FLT_MAX;
#pragma unroll
      for (int n = 0; n < 4; ++n)
        v = fminf(v, fmaf(-2.f, acc[m][n][e], cnv[n]));
#pragma unroll
      for (int s = 1; s < 16; s <<= 1) v = fminf(v, __shfl_xor(v, s));
      if (lr == 0) amin[n0 + wave * 32 + m * 16 + lg * 4 + e] = fsort(v);
    }
  }
}

// ============================ fused GEMM + argmin ============================

__global__ __launch_bounds__(256, 4) void assign_mfma(
    const unsigned short* __restrict__ Xb, const unsigned short* __restrict__ Cb,
    const float* __restrict__ X32, const float* __restrict__ C32,
    const float* __restrict__ Ct, const float* __restrict__ cn,
    u32* __restrict__ amin, u64* __restrict__ best) {
  __shared__ unsigned short As[128 * 64];   // [row][chunk-swizzled d]
  __shared__ unsigned short Bs[128 * 64];

  const int t = threadIdx.x;
  const int lane = t & 63, wave = t >> 6;
  const int wr = wave >> 1, wc = wave & 1;
  const int n0 = blockIdx.x * 128;
  const int k0 = blockIdx.y * 128;
  const int lr = lane & 15, lg = lane >> 4;
  const int srow = lane >> 3, schunk = lane & 7;
  const int xr = lr & 7;                    // read-side swizzle key (row&7 == lr&7)

  f32x4 acc[4][4];
  f32x4 z = {0.f, 0.f, 0.f, 0.f};
#pragma unroll
  for (int m = 0; m < 4; ++m)
#pragma unroll
    for (int n = 0; n < 4; ++n) acc[m][n] = z;

  const unsigned short* gA = Xb + (size_t)(n0 + wave * 32 + srow) * DDIM + schunk * 8;
  const unsigned short* gB = Cb + (size_t)(k0 + wave * 32 + srow) * DDIM + schunk * 8;

  for (int it = 0; it < DDIM / 64; ++it) {
#pragma unroll
    for (int i = 0; i < 4; ++i) {
      GLOAD_LDS16(gA + (size_t)i * 8 * DDIM, As + (wave * 32 + i * 8) * 64);
      GLOAD_LDS16(gB + (size_t)i * 8 * DDIM, Bs + (wave * 32 + i * 8) * 64);
    }
    gA += 64; gB += 64;
    __syncthreads();
#pragma unroll
    for (int dk = 0; dk < 2; ++dk) {
      s16x8 af[4], bfr[4];
      const int c = (dk * 4 + lg) ^ xr;     // physical chunk
#pragma unroll
      for (int m = 0; m < 4; ++m)
        af[m] = *(const s16x8*)(As + (wr * 64 + m * 16 + lr) * 64 + c * 8);
#pragma unroll
      for (int n = 0; n < 4; ++n)
        bfr[n] = *(const s16x8*)(Bs + (wc * 64 + n * 16 + lr) * 64 + c * 8);
#pragma unroll
      for (int m = 0; m < 4; ++m)
#pragma unroll
        for (int n = 0; n < 4; ++n)
          acc[m][n] = __builtin_amdgcn_mfma_f32_16x16x32_bf16(af[m], bfr[n], acc[m][n], 0, 0, 0);
    }
    __syncthreads();
  }

  // ---------------- epilogue: approx min + exact rescore ----------------
  float cnv[4];
#pragma unroll
  for (int n = 0; n < 4; ++n) cnv[n] = cn[k0 + wc * 64 + n * 16 + lr];

#pragma unroll
  for (int m = 0; m < 4; ++m) {
    float sc[4][4];  // [n][e]
#pragma unroll
    for (int n = 0; n < 4; ++n)
#pragma unroll
      for (int e = 0; e < 4; ++e) sc[n][e] = fmaf(-2.f, acc[m][n][e], cnv[n]);

    float th[4];
#pragma unroll
    for (int e = 0; e < 4; ++e) {
      float v = fminf(fminf(sc[0][e], sc[1][e]), fminf(sc[2][e], sc[3][e]));
      u32 key = fsort(v);
#pragma unroll
      for (int s = 1; s < 16; s <<= 1) {
        u32 o = __shfl_xor(key, s);
        key = key < o ? key : o;
      }
      int row = n0 + wr * 64 + m * 16 + lg * 4 + e;
      u32 mr = key;
      if (lr == 0) {
        u32 old = atomicMin(&amin[row], key);
        mr = old < key ? old : key;
      }
      mr = __shfl(mr, lane & 48);
      th[e] = funsort(mr) + 1.5f;   // margin ~ 7 sigma of bf16-approx error diff
    }

#pragma unroll
    for (int n = 0; n < 4; ++n) {
#pragma unroll
      for (int e = 0; e < 4; ++e) {
        int kq = k0 + wc * 64 + n * 16 + lr;
        bool cand = (kq < KCOLS) && (sc[n][e] <= th[e]);
        u64 mask = __ballot(cand);
        while (mask) {
          int src = (int)__builtin_ctzll(mask);
          mask &= mask - 1;
          int srowg = n0 + wr * 64 + m * 16 + ((src >> 4) & 3) * 4 + e;
          int skg = k0 + wc * 64 + n * 16 + (src & 15);
          float part = 0.f;
          const float* xp = X32 + (size_t)srowg * DDIM + lane;
          if (Ct) {
            const float* cp = Ct + (size_t)skg * DDIM + lane;   // coalesced
#pragma unroll
            for (int i = 0; i < 12; ++i)
              part = fmaf(xp[i * 64], cp[i * 64], part);
          } else {
            const float* cp = C32 + (size_t)lane * KCOLS + skg;
#pragma unroll
            for (int i = 0; i < 12; ++i)
              part = fmaf(xp[i * 64], cp[(size_t)i * 64 * KCOLS], part);
          }
#pragma unroll
          for (int s = 1; s < 64; s <<= 1) part += __shfl_xor(part, s);
          if (lane == 0) {
            float ex = fmaf(-2.f, part, cn[skg]);
            atomicMin(&best[srowg], ((u64)fsort(ex) << 32) | (u32)skg);
          }
        }
      }
    }
  }
}

// ============================ fp32 fallback path ============================

__global__ void cnorm_kernel(const float* __restrict__ C, float* __restrict__ cnorm,
                             int D, int K) {
  int k = blockIdx.x * blockDim.x + threadIdx.x;
  if (k >= K) return;
  float s = 0.f;
  for (int d = 0; d < D; ++d) {
    float v = C[(size_t)d * K + k];
    s = fmaf(v, v, s);
  }
  cnorm[k] = s;
}

__global__ void init_kernel(u64* best, int N) {
  int n = blockIdx.x * blockDim.x + threadIdx.x;
  if (n < N) best[n] = ~0ULL;
}

__global__ __launch_bounds__(256) void assign_kernel(
    const float* __restrict__ X, const float* __restrict__ C,
    const float* __restrict__ cnorm, u64* __restrict__ best,
    int N, int D, int K) {
  __shared__ float Xs[16][128];
  __shared__ float Cs[16][64];
  const int t = threadIdx.x;
  const int tx = t & 15, ty = t >> 4;
  const int k0 = blockIdx.x * 64;
  const int n0 = blockIdx.y * 128;
  float acc[8][4];
#pragma unroll
  for (int i = 0; i < 8; ++i)
#pragma unroll
    for (int j = 0; j < 4; ++j) acc[i][j] = 0.f;
  for (int d0 = 0; d0 < D; d0 += 16) {
#pragma unroll
    for (int v = 0; v < 2; ++v) {
      int f4 = t + v * 256;
      int row = f4 >> 2;
      int dc = (f4 & 3) * 4;
      const float4 xv = *(const float4*)&X[(size_t)(n0 + row) * D + d0 + dc];
      Xs[dc + 0][row] = xv.x; Xs[dc + 1][row] = xv.y;
      Xs[dc + 2][row] = xv.z; Xs[dc + 3][row] = xv.w;
    }
    {
      int d = t >> 4, kc = (t & 15) * 4, k = k0 + kc;
      float4 cv;
      if (k + 3 < K) cv = *(const float4*)&C[(size_t)(d0 + d) * K + k];
      else {
        cv.x = (k + 0 < K) ? C[(size_t)(d0 + d) * K + k + 0] : 0.f;
        cv.y = (k + 1 < K) ? C[(size_t)(d0 + d) * K + k + 1] : 0.f;
        cv.z = (k + 2 < K) ? C[(size_t)(d0 + d) * K + k + 2] : 0.f;
        cv.w = (k + 3 < K) ? C[(size_t)(d0 + d) * K + k + 3] : 0.f;
      }
      *(float4*)&Cs[d][kc] = cv;
    }
    __syncthreads();
#pragma unroll
    for (int d = 0; d < 16; ++d) {
      float4 a0 = *(const float4*)&Xs[d][ty * 8];
      float4 a1 = *(const float4*)&Xs[d][ty * 8 + 4];
      float4 b = *(const float4*)&Cs[d][tx * 4];
      float av[8] = {a0.x, a0.y, a0.z, a0.w, a1.x, a1.y, a1.z, a1.w};
      float bv[4] = {b.x, b.y, b.z, b.w};
#pragma unroll
      for (int i = 0; i < 8; ++i)
#pragma unroll
        for (int j = 0; j < 4; ++j) acc[i][j] = fmaf(av[i], bv[j], acc[i][j]);
    }
    __syncthreads();
  }
  float cnv[4];
#pragma unroll
  for (int j = 0; j < 4; ++j) {
    int k = k0 + tx * 4 + j;
    cnv[j] = (k < K) ? cnorm[k] : 0.f;
  }
#pragma unroll
  for (int i = 0; i < 8; ++i) {
    u64 key = ~0ULL;
#pragma unroll
    for (int j = 0; j < 4; ++j) {
      int k = k0 + tx * 4 + j;
      if (k < K) {
        float score = fmaf(-2.f, acc[i][j], cnv[j]);
        u64 cand = ((u64)fsort(score) << 32) | (unsigned)k;
        key = key < cand ? key : cand;
      }
    }
#pragma unroll
    for (int mk = 8; mk >= 1; mk >>= 1) {
      u64 other = __shfl_xor(key, mk, 16);
      key = key < other ? key : other;
    }
    if (tx == 0) atomicMin(&best[n0 + ty * 8 + i], key);
  }
}

// ---------------- shared output kernel ----------------
__global__ void out_kernel(const u64* __restrict__ best, int* __restrict__ out, int N) {
  int n = blockIdx.x * blockDim.x + threadIdx.x;
  if (n < N) out[n] = (int)(u32)(best[n] & 0xffffffffu);
}

extern "C" void kernel_launch(void* const* d_in, const int* in_sizes, int n_in,
                              void* d_out, int out_size, void* d_ws, size_t ws_size,
                              hipStream_t stream) {
  const float* X = (const float*)d_in[0];  // [N, D]
  const float* C = (const float*)d_in[1];  // [D, K]
  int* out = (int*)d_out;

  // ws layout: best | amin | cnorm | Xb | Cb | Ct
  const size_t OFF_BEST = 0;
  const size_t OFF_AMIN = 131072;
  const size_t OFF_CN   = 196608;
  const size_t OFF_XB   = 262144;
  const size_t OFF_CB   = OFF_XB + (size_t)N_ROWS * DDIM * 2;     // 25427968
  const size_t OFF_CT   = OFF_CB + (size_t)KPAD * DDIM * 2;       // 40960000
  const size_t REQ_A    = OFF_CT + (size_t)KPAD * DDIM * 4;       // 72024064

  if (ws_size >= REQ_A) {
    u64* best = (u64*)((char*)d_ws + OFF_BEST);
    u32* amin = (u32*)((char*)d_ws + OFF_AMIN);
    float* cnp = (float*)((char*)d_ws + OFF_CN);
    unsigned short* Xb = (unsigned short*)((char*)d_ws + OFF_XB);
    unsigned short* Cb = (unsigned short*)((char*)d_ws + OFF_CB);
    float* Ct = (float*)((char*)d_ws + OFF_CT);

    hipLaunchKernelGGL(prep_kernel, dim3(TRANSC_BLKS + CONVX_BLKS + CNORM_BLKS), dim3(256),
                       0, stream, X, C, Xb, Cb, Ct, cnp, best);
    hipLaunchKernelGGL(seed_mfma, dim3(N_ROWS / 128), dim3(256), 0, stream, Xb, Cb, cnp, amin);
    hipLaunchKernelGGL(assign_mfma, dim3(N_ROWS / 128, KPAD / 128), dim3(256), 0, stream,
                       Xb, Cb, X, C, Ct, cnp, amin, best);
    hipLaunchKernelGGL(out_kernel, dim3(64), dim3(256), 0, stream, best, out, N_ROWS);
  } else {
    // fp32 fallback (round-2 passing path)
    u64* best = (u64*)d_ws;
    float* cnorm = (float*)((char*)d_ws + (size_t)N_ROWS * sizeof(u64));
    hipLaunchKernelGGL(init_kernel, dim3(64), dim3(256), 0, stream, best, N_ROWS);
    hipLaunchKernelGGL(cnorm_kernel, dim3((KCOLS + 255) / 256), dim3(256), 0, stream,
                       C, cnorm, DDIM, KCOLS);
    hipLaunchKernelGGL(assign_kernel, dim3((KCOLS + 63) / 64, N_ROWS / 128), dim3(256), 0,
                       stream, X, C, cnorm, best, N_ROWS, DDIM, KCOLS);
    hipLaunchKernelGGL(out_kernel, dim3(64), dim3(256), 0, stream, best, out, N_ROWS);
  }
}